// Round 3
// baseline (186.472 us; speedup 1.0000x reference)
//
#include <hip/hip_runtime.h>

// XingLoss: x_list (P=16384, N=1024, 2) f32, scale (int scalar).
// Per row p, per segment s in [0,256): uses points x[3s..3s+3] (max idx 768,
// i.e. floats [0,1540) of each 2048-float row; wraparound point never used).
//   direct = cross(v1,v2) >= 0   (norm product positive -> sign of cross)
//   sina   = cross(v1,v3) / (|v1||v3|)
//   term   = direct ? relu(-sina) : relu(sina)
// out = scale * sum(term) / (segn * P).
//
// R2 -> R3: total 182us, but top-5 dispatches are harness poison fills
// (512MB ws fill @77us + d_in restore ~37us = ~120-145us fixed overhead).
// Our kernels ~40-60us vs ~16us memory floor. This round: 8 rows/block
// (grid 2048, 8 blocks/CU), double-buffered LDS with one barrier/row and
// register prefetch of the next row, one block-reduce per 8 rows.

#define N_PTS     1024
#define SEGN      (N_PTS / 4)        // 256
#define BLOCK     256                // thread t -> segment t of current row
#define RPB       8                  // rows per block
#define ROW_F4    385                // ceil(1540/4) float4s staged per row
#define ROW_STRIDE_F4 (N_PTS * 2 / 4) // 512 float4 per full row

__global__ __launch_bounds__(BLOCK)
void xing_partial_kernel(const float* __restrict__ x,
                         float*       __restrict__ partial)
{
    const int t = threadIdx.x;
    const bool has2 = (t < ROW_F4 - BLOCK);   // t < 129 loads a second f4

    __shared__ float4 buf[2][ROW_F4];         // 12320 B

    const float4* src = reinterpret_cast<const float4*>(x)
                      + (size_t)blockIdx.x * RPB * ROW_STRIDE_F4;

    // Prefetch row 0.
    buf[0][t] = src[t];
    if (has2) buf[0][BLOCK + t] = src[BLOCK + t];
    __syncthreads();

    float acc = 0.0f;

    #pragma unroll
    for (int r = 0; r < RPB; ++r) {
        // Issue next row's global loads (no wait until the ds_write below).
        float4 n0, n1;
        if (r + 1 < RPB) {
            const float4* nsrc = src + (size_t)(r + 1) * ROW_STRIDE_F4;
            n0 = nsrc[t];
            if (has2) n1 = nsrc[BLOCK + t];
        }

        // Compute segment t of row r from LDS.
        const float2* pts = reinterpret_cast<const float2*>(buf[r & 1]);
        const float2 a = pts[3 * t + 0];
        const float2 b = pts[3 * t + 1];
        const float2 c = pts[3 * t + 2];
        const float2 d = pts[3 * t + 3];

        const float v1x = b.x - a.x, v1y = b.y - a.y;
        const float v2x = c.x - b.x, v2y = c.y - b.y;
        const float v3x = d.x - c.x, v3y = d.y - c.y;

        const float cross12 = v1x * v2y - v1y * v2x;
        const float cross13 = v1x * v3y - v1y * v3x;

        const float n1sq = v1x * v1x + v1y * v1y;
        const float n3sq = v3x * v3x + v3y * v3y;
        const float sina = cross13 * rsqrtf(n1sq * n3sq);

        acc += (cross12 >= 0.0f) ? fmaxf(-sina, 0.0f) : fmaxf(sina, 0.0f);

        // Park next row into the other LDS buffer.
        if (r + 1 < RPB) {
            float4* dst = buf[(r + 1) & 1];
            dst[t] = n0;
            if (has2) dst[BLOCK + t] = n1;
        }
        __syncthreads();
    }

    // Block reduction (wave-64 shuffle, then 4 wave sums via LDS).
    #pragma unroll
    for (int off = 32; off > 0; off >>= 1)
        acc += __shfl_down(acc, off, 64);

    __shared__ float wsum[BLOCK / 64];
    const int lane = t & 63;
    const int wid  = t >> 6;
    if (lane == 0) wsum[wid] = acc;
    __syncthreads();

    if (t == 0)
        partial[blockIdx.x] = (wsum[0] + wsum[1]) + (wsum[2] + wsum[3]);
}

// Reduce (P/RPB)=2048 partials -> scalar.  8KB read, one block.
__global__ __launch_bounds__(BLOCK)
void xing_reduce_kernel(const float* __restrict__ partial,
                        const int*   __restrict__ scale_p,
                        float*       __restrict__ out,
                        int P)
{
    const int t = threadIdx.x;
    const int nf4 = (P / RPB) / 4;   // 512
    const float4* pf4 = reinterpret_cast<const float4*>(partial);

    float sum = 0.0f;
    #pragma unroll
    for (int i = t; i < nf4; i += BLOCK) {
        float4 v = pf4[i];
        sum += (v.x + v.y) + (v.z + v.w);
    }

    #pragma unroll
    for (int off = 32; off > 0; off >>= 1)
        sum += __shfl_down(sum, off, 64);

    __shared__ float wsum[BLOCK / 64];
    const int lane = t & 63;
    const int wid  = t >> 6;
    if (lane == 0) wsum[wid] = sum;
    __syncthreads();

    if (t == 0) {
        const float total = (wsum[0] + wsum[1]) + (wsum[2] + wsum[3]);
        out[0] = total * (float)(*scale_p) / ((float)SEGN * (float)P);
    }
}

extern "C" void kernel_launch(void* const* d_in, const int* in_sizes, int n_in,
                              void* d_out, int out_size, void* d_ws, size_t ws_size,
                              hipStream_t stream)
{
    const float* x       = (const float*)d_in[0];
    const int*   scale_p = (const int*)d_in[1];
    float*       out     = (float*)d_out;
    float*       partial = (float*)d_ws;

    const int P = in_sizes[0] / (N_PTS * 2);   // 16384

    xing_partial_kernel<<<P / RPB, BLOCK, 0, stream>>>(x, partial);
    xing_reduce_kernel<<<1, BLOCK, 0, stream>>>(partial, scale_p, out, P);
}

// Round 4
// 183.349 us; speedup vs baseline: 1.0170x; 1.0170x over previous
//
#include <hip/hip_runtime.h>

// XingLoss: x_list (P=16384, N=1024, 2) f32, scale (int scalar).
// Per row p, per segment s in [0,256): uses floats 6s..6s+7 (pts 3s..3s+3).
//   direct = cross(v1,v2) >= 0   (norm product positive -> sign of cross)
//   sina   = cross(v1,v3) / (|v1||v3|)
//   term   = direct ? relu(-sina) : relu(sina)
// out = scale * sum(term) / (segn * P).
//
// R3 -> R4: the 512MB ws poison fill before every launch evicts L3 ->
// input reads are HBM-cold; fixed harness overhead ~144us, our slice ~40us
// vs 16us floor. The LDS double-buffer forced vmcnt(0)+barrier per row
// (one row of loads in flight, ~900cyc bubble/iter) and bought nothing
// (zero data reuse). Now: direct stride-24B float2 loads (8B aligned,
// wave-contiguous spans -> full line utilization), no LDS, no loop
// barriers, 8 rows accumulated in registers -> compiler pipelines loads
// across all iterations. TA split cost of strided loads (~10us) < HBM
// floor (16us), so still HBM-bound.

#define N_PTS  1024
#define SEGN   (N_PTS / 4)          // 256
#define BLOCK  256                  // thread t -> segment t
#define RPB    8                    // rows per block; grid = P/RPB = 2048
#define ROW_F  (N_PTS * 2)          // 2048 floats per row

__global__ __launch_bounds__(BLOCK)
void xing_partial_kernel(const float* __restrict__ x,
                         float*       __restrict__ partial)
{
    const int t = threadIdx.x;
    // Floats 6t..6t+7 of this block's first row; byte addr 24t -> 8B aligned.
    const float* base = x + (size_t)blockIdx.x * RPB * ROW_F + 6 * t;

    float acc = 0.0f;

    #pragma unroll
    for (int r = 0; r < RPB; ++r) {
        const float2* q = reinterpret_cast<const float2*>(base + r * ROW_F);
        const float2 a = q[0];
        const float2 b = q[1];
        const float2 c = q[2];
        const float2 d = q[3];

        const float v1x = b.x - a.x, v1y = b.y - a.y;
        const float v2x = c.x - b.x, v2y = c.y - b.y;
        const float v3x = d.x - c.x, v3y = d.y - c.y;

        const float cross12 = v1x * v2y - v1y * v2x;
        const float cross13 = v1x * v3y - v1y * v3x;

        const float n1sq = v1x * v1x + v1y * v1y;
        const float n3sq = v3x * v3x + v3y * v3y;
        const float sina = cross13 * rsqrtf(n1sq * n3sq);

        acc += (cross12 >= 0.0f) ? fmaxf(-sina, 0.0f) : fmaxf(sina, 0.0f);
    }

    // Block reduction: wave-64 shuffle, then 4 wave sums via LDS.
    #pragma unroll
    for (int off = 32; off > 0; off >>= 1)
        acc += __shfl_down(acc, off, 64);

    __shared__ float wsum[BLOCK / 64];
    const int lane = t & 63;
    const int wid  = t >> 6;
    if (lane == 0) wsum[wid] = acc;
    __syncthreads();

    if (t == 0)
        partial[blockIdx.x] = (wsum[0] + wsum[1]) + (wsum[2] + wsum[3]);
}

// Reduce (P/RPB)=2048 partials -> scalar.  8KB read, one block.
__global__ __launch_bounds__(BLOCK)
void xing_reduce_kernel(const float* __restrict__ partial,
                        const int*   __restrict__ scale_p,
                        float*       __restrict__ out,
                        int P)
{
    const int t = threadIdx.x;
    const int nf4 = (P / RPB) / 4;   // 512
    const float4* pf4 = reinterpret_cast<const float4*>(partial);

    float sum = 0.0f;
    #pragma unroll
    for (int i = t; i < nf4; i += BLOCK) {
        float4 v = pf4[i];
        sum += (v.x + v.y) + (v.z + v.w);
    }

    #pragma unroll
    for (int off = 32; off > 0; off >>= 1)
        sum += __shfl_down(sum, off, 64);

    __shared__ float wsum[BLOCK / 64];
    const int lane = t & 63;
    const int wid  = t >> 6;
    if (lane == 0) wsum[wid] = sum;
    __syncthreads();

    if (t == 0) {
        const float total = (wsum[0] + wsum[1]) + (wsum[2] + wsum[3]);
        out[0] = total * (float)(*scale_p) / ((float)SEGN * (float)P);
    }
}

extern "C" void kernel_launch(void* const* d_in, const int* in_sizes, int n_in,
                              void* d_out, int out_size, void* d_ws, size_t ws_size,
                              hipStream_t stream)
{
    const float* x       = (const float*)d_in[0];
    const int*   scale_p = (const int*)d_in[1];
    float*       out     = (float*)d_out;
    float*       partial = (float*)d_ws;

    const int P = in_sizes[0] / (N_PTS * 2);   // 16384

    xing_partial_kernel<<<P / RPB, BLOCK, 0, stream>>>(x, partial);
    xing_reduce_kernel<<<1, BLOCK, 0, stream>>>(partial, scale_p, out, P);
}